// Round 3
// baseline (503.749 us; speedup 1.0000x reference)
//
#include <hip/hip_runtime.h>
#include <hip/hip_bf16.h>

typedef __hip_bfloat16 bf16;
typedef __attribute__((ext_vector_type(8))) short          bf16x8;
typedef __attribute__((ext_vector_type(4))) float          f32x4;
typedef __attribute__((ext_vector_type(8))) unsigned short u16x8;

#define C_DIM 512
#define NSP   4096

__device__ __forceinline__ unsigned short f2bu(float x) {
  bf16 h = __float2bfloat16(x);
  return *reinterpret_cast<unsigned short*>(&h);
}

// ---------------- f32 -> bf16 convert (512x512 weight) ----------------
__global__ __launch_bounds__(256) void cvt_bf16(const float* __restrict__ s,
                                                bf16* __restrict__ d) {
  const int i = (blockIdx.x * 256 + threadIdx.x) * 4;
  const float4 v = *reinterpret_cast<const float4*>(s + i);
  d[i + 0] = __float2bfloat16(v.x);
  d[i + 1] = __float2bfloat16(v.y);
  d[i + 2] = __float2bfloat16(v.z);
  d[i + 3] = __float2bfloat16(v.w);
}

// ---------------- x (B,C,N) f32 -> XT (B*N, C) bf16 ----------------
__global__ __launch_bounds__(256) void transpose_x(const float* __restrict__ x,
                                                   bf16* __restrict__ xt) {
  __shared__ float tile[32][33];
  const int n0 = blockIdx.x * 32, c0 = blockIdx.y * 32, b = blockIdx.z;
  const int tx = threadIdx.x & 31, ty = threadIdx.x >> 5;
  const float* src = x + ((size_t)b * C_DIM + c0) * NSP + n0;
  #pragma unroll
  for (int i = 0; i < 32; i += 8)
    tile[ty + i][tx] = src[(size_t)(ty + i) * NSP + tx];
  __syncthreads();
  bf16* dst = xt + ((size_t)b * NSP + n0) * C_DIM + c0;
  #pragma unroll
  for (int i = 0; i < 32; i += 8)
    dst[(size_t)(ty + i) * C_DIM + tx] = __float2bfloat16(tile[tx][ty + i]);
}

// ---------------- NT MFMA GEMM: C[m,n] = sum_k A[m,k]*B[n,k] ----------------
// 128x128 tile, BK=32, 256 threads, 16x16x32 bf16 MFMA, 2-phase dbuf.
// EPI: 0 bf16 +bias (row-major ldc)
//      4 f32  +bias+resid, transposed store (out[(b*C+n)*NSP + m], b=m>>12)
//      5 fused theta/phi/g: n<512 -> Cout  (v+bias )*scale
//                           <1024 -> Cout2 (v+bias2)
//                           else  -> Cout3 (v+bias3) transposed (B,C,N)
template<int EPI>
__global__ __launch_bounds__(256)
void gemm_nt(const bf16* __restrict__ A, const bf16* __restrict__ B,
             const float* __restrict__ bias, const float* __restrict__ resid,
             void* __restrict__ Cout,
             int K, int lda, int ldb, int ldc, float scale,
             const float* __restrict__ bias2, const float* __restrict__ bias3,
             void* __restrict__ Cout2, void* __restrict__ Cout3)
{
  __shared__ char smem[2][16384];
  const int t  = threadIdx.x;
  const int m0 = blockIdx.y * 128;
  const int n0 = blockIdx.x * 128;
  A += (size_t)m0 * lda;
  B += (size_t)n0 * ldb;

  const int lane = t & 63;
  const int wv = t >> 6;
  const int wr = wv >> 1, wc = wv & 1;

  f32x4 acc[4][4];
  #pragma unroll
  for (int i = 0; i < 4; ++i)
    #pragma unroll
    for (int j = 0; j < 4; ++j) acc[i][j] = (f32x4)0.0f;

  auto STAGE = [&](int buf, int kt) {
    const bf16* a = A + kt * 32;
    const bf16* b = B + kt * 32;
    #pragma unroll
    for (int i = 0; i < 2; ++i) {
      const int chunk = i * 256 + t;
      const int row = chunk >> 2, gp = chunk & 3;
      const int gg = gp ^ ((row >> 1) & 3);
      __builtin_amdgcn_global_load_lds(
          (const __attribute__((address_space(1))) unsigned int*)(a + (size_t)row * lda + gg * 8),
          (__attribute__((address_space(3))) unsigned int*)(&smem[buf][chunk * 16]),
          16, 0, 0);
    }
    #pragma unroll
    for (int i = 0; i < 2; ++i) {
      const int chunk = i * 256 + t;
      const int row = chunk >> 2, gp = chunk & 3;
      const int gg = gp ^ ((row >> 1) & 3);
      __builtin_amdgcn_global_load_lds(
          (const __attribute__((address_space(1))) unsigned int*)(b + (size_t)row * ldb + gg * 8),
          (__attribute__((address_space(3))) unsigned int*)(&smem[buf][8192 + chunk * 16]),
          16, 0, 0);
    }
  };

  const int nk = K >> 5;
  STAGE(0, 0);
  int cur = 0;
  const int r16 = lane & 15;
  const int gx  = ((lane >> 4) ^ ((r16 >> 1) & 3)) * 16;
  const int arow = wr * 64 + r16;
  const int brow = wc * 64 + r16;

  for (int kt = 0; kt < nk; ++kt) {
    __syncthreads();
    if (kt + 1 < nk) STAGE(cur ^ 1, kt + 1);
    bf16x8 af[4], bg[4];
    #pragma unroll
    for (int i = 0; i < 4; ++i)
      af[i] = *reinterpret_cast<const bf16x8*>(&smem[cur][(arow + i * 16) * 64 + gx]);
    #pragma unroll
    for (int j = 0; j < 4; ++j)
      bg[j] = *reinterpret_cast<const bf16x8*>(&smem[cur][8192 + (brow + j * 16) * 64 + gx]);
    #pragma unroll
    for (int i = 0; i < 4; ++i)
      #pragma unroll
      for (int j = 0; j < 4; ++j)
        acc[i][j] = __builtin_amdgcn_mfma_f32_16x16x32_bf16(af[i], bg[j], acc[i][j], 0, 0, 0);
    cur ^= 1;
  }

  const int mq = (lane >> 4) * 4;
  const int nc = lane & 15;
  #pragma unroll
  for (int i = 0; i < 4; ++i) {
    #pragma unroll
    for (int j = 0; j < 4; ++j) {
      const int mm = m0 + wr * 64 + i * 16 + mq;
      const int nn = n0 + wc * 64 + j * 16 + nc;
      const f32x4 v = acc[i][j];
      if (EPI == 0) {
        const float bi = bias[nn];
        bf16* o = (bf16*)Cout;
        #pragma unroll
        for (int q = 0; q < 4; ++q)
          o[(size_t)(mm + q) * ldc + nn] = __float2bfloat16(v[q] + bi);
      } else if (EPI == 4) {
        const float bi = bias[nn];
        const int b = mm >> 12, ms = mm & (NSP - 1);
        const size_t off = ((size_t)b * C_DIM + nn) * NSP + ms;
        float* o = (float*)Cout + off;
        const float* r = resid + off;
        #pragma unroll
        for (int q = 0; q < 4; ++q) o[q] = v[q] + bi + r[q];
      } else {  // EPI == 5
        const int sec = nn >> 9;
        const int nl  = nn & 511;
        if (sec == 0) {
          const float bi = bias[nl];
          bf16* o = (bf16*)Cout;
          #pragma unroll
          for (int q = 0; q < 4; ++q)
            o[(size_t)(mm + q) * 512 + nl] = __float2bfloat16((v[q] + bi) * scale);
        } else if (sec == 1) {
          const float bi = bias2[nl];
          bf16* o = (bf16*)Cout2;
          #pragma unroll
          for (int q = 0; q < 4; ++q)
            o[(size_t)(mm + q) * 512 + nl] = __float2bfloat16(v[q] + bi);
        } else {
          const float bi = bias3[nl];
          const int b = mm >> 12, ms = mm & (NSP - 1);
          bf16* o = (bf16*)Cout3 + ((size_t)b * C_DIM + nl) * NSP + ms;
          #pragma unroll
          for (int q = 0; q < 4; ++q) o[q] = __float2bfloat16(v[q] + bi);
        }
      }
    }
  }
}

// ---------------- flash attention: O = softmax(Q K^T) V ----------------
// Q = THT pre-scaled (B*N,C) bf16; K = PHT (B*N,C); V = G2 (B,C,N); O = ZT (B*N,C)
// grid (64 q-tiles, 4 batches), 256 thr, wave w owns q rows [q0+16w, +16).
// KV chunk 32, double-buffered. LDS 132KB, 1 block/CU -> VGPR budget 512.
__global__ __launch_bounds__(256, 1)
void flash_attn(const bf16* __restrict__ Q, const bf16* __restrict__ Kp,
                const bf16* __restrict__ Vp, bf16* __restrict__ O)
{
  __shared__ char smem[135168];   // K dbuf 64K | V dbuf 64K | P 4x1K
  const int t = threadIdx.x;
  const int lane = t & 63;
  const int w = t >> 6;
  const int b = blockIdx.y;
  const int q0 = blockIdx.x * 64;
  const size_t bq = (size_t)b * NSP;
  const int r16 = lane & 15, g4 = lane >> 4;

  // Q fragments: 16 k-steps, lane holds row (q0+16w+r16), k = s*32 + g4*8 + j
  const bf16* qptr = Q + (bq + q0 + w * 16 + r16) * 512 + g4 * 8;
  bf16x8 qf[16];
  #pragma unroll
  for (int s = 0; s < 16; ++s)
    qf[s] = *reinterpret_cast<const bf16x8*>(qptr + s * 32);

  f32x4 oacc[32];
  #pragma unroll
  for (int i = 0; i < 32; ++i) oacc[i] = (f32x4)0.0f;
  float m[4], l[4];
  #pragma unroll
  for (int r = 0; r < 4; ++r) { m[r] = -1e30f; l[r] = 0.0f; }

  char* PB = smem + 131072 + w * 1024;

  auto STAGE = [&](int buf, int kt) {
    const int kv0 = kt * 32;
    char* kd = smem + buf * 32768;
    char* vd = smem + 65536 + buf * 32768;
    #pragma unroll
    for (int i = 0; i < 8; ++i) {
      const int ch = i * 256 + t;
      const int row = ch >> 6, gp = ch & 63;
      const int g = gp ^ (row & 7);
      __builtin_amdgcn_global_load_lds(
          (const __attribute__((address_space(1))) unsigned int*)(Kp + (bq + kv0 + row) * 512 + g * 8),
          (__attribute__((address_space(3))) unsigned int*)(kd + ch * 16), 16, 0, 0);
    }
    #pragma unroll
    for (int i = 0; i < 8; ++i) {
      const int ch = i * 256 + t;
      const int c = ch >> 2, gp = ch & 3;
      const int g = gp ^ ((c >> 1) & 3);
      __builtin_amdgcn_global_load_lds(
          (const __attribute__((address_space(1))) unsigned int*)(Vp + ((size_t)b * C_DIM + c) * NSP + kv0 + g * 8),
          (__attribute__((address_space(3))) unsigned int*)(vd + ch * 16), 16, 0, 0);
    }
  };

  STAGE(0, 0);
  int cur = 0;

  for (int kt = 0; kt < 128; ++kt) {
    __syncthreads();                       // vmcnt(0) drain: buf `cur` ready
    if (kt + 1 < 128) STAGE(cur ^ 1, kt + 1);
    const char* kb = smem + cur * 32768;
    const char* vb = smem + 65536 + cur * 32768;

    // QK^T: S strip 16q x 32kv (2 n-tiles)
    f32x4 s0 = (f32x4)0.0f, s1 = (f32x4)0.0f;
    #pragma unroll
    for (int s = 0; s < 16; ++s) {
      const int row1 = 16 + r16;
      bf16x8 k0 = *(const bf16x8*)(kb + r16 * 1024 + (((s * 4 + g4) ^ (r16 & 7)) * 16));
      bf16x8 k1 = *(const bf16x8*)(kb + row1 * 1024 + (((s * 4 + g4) ^ (row1 & 7)) * 16));
      s0 = __builtin_amdgcn_mfma_f32_16x16x32_bf16(qf[s], k0, s0, 0, 0, 0);
      s1 = __builtin_amdgcn_mfma_f32_16x16x32_bf16(qf[s], k1, s1, 0, 0, 0);
    }

    // online softmax, defer-max (THR=8)
    float pmax[4];
    #pragma unroll
    for (int r = 0; r < 4; ++r) pmax[r] = fmaxf(s0[r], s1[r]);
    #pragma unroll
    for (int msk = 1; msk < 16; msk <<= 1)
      #pragma unroll
      for (int r = 0; r < 4; ++r) pmax[r] = fmaxf(pmax[r], __shfl_xor(pmax[r], msk));
    bool need = false;
    #pragma unroll
    for (int r = 0; r < 4; ++r) need |= (pmax[r] > m[r] + 8.0f);
    if (__any(need)) {
      #pragma unroll
      for (int r = 0; r < 4; ++r) {
        const float mn = fmaxf(m[r], pmax[r]);
        const float f = __expf(m[r] - mn);
        m[r] = mn; l[r] *= f;
        #pragma unroll
        for (int i = 0; i < 32; ++i) oacc[i][r] *= f;
      }
    }
    float p[8];
    #pragma unroll
    for (int r = 0; r < 4; ++r) {
      p[r]     = __expf(s0[r] - m[r]);
      p[4 + r] = __expf(s1[r] - m[r]);
    }
    float rs[4];
    #pragma unroll
    for (int r = 0; r < 4; ++r) rs[r] = p[r] + p[4 + r];
    #pragma unroll
    for (int msk = 1; msk < 16; msk <<= 1)
      #pragma unroll
      for (int r = 0; r < 4; ++r) rs[r] += __shfl_xor(rs[r], msk);
    #pragma unroll
    for (int r = 0; r < 4; ++r) l[r] += rs[r];

    // P strip -> LDS (bf16, swizzled), wave-private
    #pragma unroll
    for (int tt = 0; tt < 2; ++tt)
      #pragma unroll
      for (int r = 0; r < 4; ++r) {
        const int q = g4 * 4 + r, kv = tt * 16 + r16;
        *(unsigned short*)(PB + q * 64 + (((kv >> 3) ^ ((q >> 1) & 3)) * 16) + (kv & 7) * 2)
            = f2bu(p[tt * 4 + r]);
      }
    bf16x8 pf = *(const bf16x8*)(PB + r16 * 64 + ((g4 ^ ((r16 >> 1) & 3)) * 16));

    // PV: O[16q x 512c] += P[16x32] V[32x512]
    #pragma unroll
    for (int tt = 0; tt < 32; ++tt) {
      const int c = tt * 16 + r16;
      bf16x8 vf = *(const bf16x8*)(vb + c * 64 + ((g4 ^ ((c >> 1) & 3)) * 16));
      oacc[tt] = __builtin_amdgcn_mfma_f32_16x16x32_bf16(pf, vf, oacc[tt], 0, 0, 0);
    }
    cur ^= 1;
  }

  // epilogue: O/l -> LDS transpose -> coalesced store
  __syncthreads();
  char* OB = smem + w * 16384;
  float rinv[4];
  #pragma unroll
  for (int r = 0; r < 4; ++r) rinv[r] = 1.0f / l[r];
  #pragma unroll
  for (int tt = 0; tt < 32; ++tt)
    #pragma unroll
    for (int r = 0; r < 4; ++r) {
      const int q = g4 * 4 + r, c = tt * 16 + r16;
      *(unsigned short*)(OB + q * 1024 + c * 2) = f2bu(oacc[tt][r] * rinv[r]);
    }
  unsigned short* ob = reinterpret_cast<unsigned short*>(O) + (bq + q0 + w * 16) * 512;
  #pragma unroll
  for (int it = 0; it < 16; ++it) {
    u16x8 v = *(const u16x8*)(OB + it * 1024 + lane * 16);
    *reinterpret_cast<u16x8*>(ob + it * 512 + lane * 8) = v;
  }
}

extern "C" void kernel_launch(void* const* d_in, const int* in_sizes, int n_in,
                              void* d_out, int out_size, void* d_ws, size_t ws_size,
                              hipStream_t stream)
{
  const float* x     = (const float*)d_in[0];
  const float* w_th  = (const float*)d_in[1];
  const float* b_th  = (const float*)d_in[2];
  const float* w_ph  = (const float*)d_in[3];
  const float* b_ph  = (const float*)d_in[4];
  const float* w_g   = (const float*)d_in[5];
  const float* b_g   = (const float*)d_in[6];
  const float* w_out = (const float*)d_in[7];
  const float* b_out = (const float*)d_in[8];

  const size_t NC = (size_t)16384 * C_DIM;
  char* p = (char*)d_ws;
  auto take = [&](size_t bytes) {
    char* r = p; p += (bytes + 255) & ~(size_t)255; return r;
  };
  bf16* XT   = (bf16*)take(NC * 2);
  bf16* YT   = (bf16*)take(NC * 2);
  bf16* THT  = (bf16*)take(NC * 2);   // pre-scaled theta
  bf16* PHT  = (bf16*)take(NC * 2);
  bf16* G2   = (bf16*)take(NC * 2);   // (B,C,N)
  bf16* ZT   = (bf16*)take(NC * 2);
  bf16* WCAT = (bf16*)take((size_t)1536 * 512 * 2);  // [th|ph|g]
  bf16* WG   = (bf16*)take((size_t)512 * 512 * 2);
  bf16* WOUT = (bf16*)take((size_t)512 * 512 * 2);

  const dim3 blk(256);
  const float scale = 0.044194173824159216f;  // 512^-0.5

  cvt_bf16<<<dim3(256), blk, 0, stream>>>(w_th,  WCAT);
  cvt_bf16<<<dim3(256), blk, 0, stream>>>(w_ph,  WCAT + (size_t)512 * 512);
  cvt_bf16<<<dim3(256), blk, 0, stream>>>(w_g,   WCAT + (size_t)1024 * 512);
  cvt_bf16<<<dim3(256), blk, 0, stream>>>(w_g,   WG);
  cvt_bf16<<<dim3(256), blk, 0, stream>>>(w_out, WOUT);

  transpose_x<<<dim3(NSP / 32, C_DIM / 32, 4), blk, 0, stream>>>(x, XT);

  // Y = g-conv(x)
  gemm_nt<0><<<dim3(4, 128), blk, 0, stream>>>(XT, WG, b_g, nullptr, YT,
      512, 512, 512, 512, 1.0f, nullptr, nullptr, nullptr, nullptr);
  // fused theta(scaled)/phi/g from Y
  gemm_nt<5><<<dim3(12, 128), blk, 0, stream>>>(YT, WCAT, b_th, nullptr, THT,
      512, 512, 512, 512, scale, b_ph, b_g, PHT, G2);
  // flash attention -> ZT
  flash_attn<<<dim3(64, 4), blk, 0, stream>>>(THT, PHT, G2, ZT);
  // out = x + out-conv(z)
  gemm_nt<4><<<dim3(4, 128), blk, 0, stream>>>(ZT, WOUT, b_out, x, d_out,
      512, 512, 512, 512, 1.0f, nullptr, nullptr, nullptr, nullptr);
}

// Round 4
// 346.691 us; speedup vs baseline: 1.4530x; 1.4530x over previous
//
#include <hip/hip_runtime.h>
#include <hip/hip_bf16.h>

typedef __hip_bfloat16 bf16;
typedef __attribute__((ext_vector_type(8))) short          bf16x8;
typedef __attribute__((ext_vector_type(4))) float          f32x4;

#define C_DIM 512
#define NSP   4096

// ---------------- f32 -> bf16 convert (512x512 weight) ----------------
__global__ __launch_bounds__(256) void cvt_bf16(const float* __restrict__ s,
                                                bf16* __restrict__ d) {
  const int i = (blockIdx.x * 256 + threadIdx.x) * 4;
  const float4 v = *reinterpret_cast<const float4*>(s + i);
  d[i + 0] = __float2bfloat16(v.x);
  d[i + 1] = __float2bfloat16(v.y);
  d[i + 2] = __float2bfloat16(v.z);
  d[i + 3] = __float2bfloat16(v.w);
}

// ---------------- x (B,C,N) f32 -> XT (B*N, C) bf16 ----------------
__global__ __launch_bounds__(256) void transpose_x(const float* __restrict__ x,
                                                   bf16* __restrict__ xt) {
  __shared__ float tile[32][33];
  const int n0 = blockIdx.x * 32, c0 = blockIdx.y * 32, b = blockIdx.z;
  const int tx = threadIdx.x & 31, ty = threadIdx.x >> 5;
  const float* src = x + ((size_t)b * C_DIM + c0) * NSP + n0;
  #pragma unroll
  for (int i = 0; i < 32; i += 8)
    tile[ty + i][tx] = src[(size_t)(ty + i) * NSP + tx];
  __syncthreads();
  bf16* dst = xt + ((size_t)b * NSP + n0) * C_DIM + c0;
  #pragma unroll
  for (int i = 0; i < 32; i += 8)
    dst[(size_t)(ty + i) * C_DIM + tx] = __float2bfloat16(tile[tx][ty + i]);
}

// ---------------- Linv: Lp[16384][64] partial sums -> 1/rowsum ----------------
__global__ __launch_bounds__(256) void lreduce(const float* __restrict__ Lp,
                                               float* __restrict__ Linv) {
  const int r = blockIdx.x * 256 + threadIdx.x;   // 0..16383
  const float4* p = reinterpret_cast<const float4*>(Lp + (size_t)r * 64);
  float s = 0.0f;
  #pragma unroll
  for (int i = 0; i < 16; ++i) { const float4 v = p[i]; s += (v.x + v.y) + (v.z + v.w); }
  Linv[r] = 1.0f / s;
}

// ---------------- NT MFMA GEMM: C[m,n] = sum_k A[m,k]*B[n,k] ----------------
// 128x128 tile, BK=32, 256 threads, 16x16x32 bf16 MFMA, 2-phase dbuf.
// All grids have nwg % 8 == 0; bijective XCD-chunk swizzle (m204) applied.
// EPI: 0 bf16 +bias (row-major ldc)
//      4 f32  +bias+resid, transposed store (out[(b*C+n)*NSP + m], b=m>>12)
//      5 fused theta/phi/g: n<512 -> Cout  (v+bias )*scale
//                           <1024 -> Cout2 (v+bias2)
//                           else  -> Cout3 (v+bias3) transposed (B,C,N)
//      6 P = exp(v) bf16 (ldc; +bz*sC) and row-sum partials -> aux[(bz*4096+row)*64 + bx*2+wc]
//      7 bf16 v * auxLinv[bz*4096+row], out row-major ldc=512 (+bz rows offset)
template<int EPI>
__global__ __launch_bounds__(256)
void gemm_nt(const bf16* __restrict__ A, const bf16* __restrict__ B,
             const float* __restrict__ bias, const float* __restrict__ resid,
             void* __restrict__ Cout,
             int K, int lda, int ldb, int ldc, float scale,
             const float* __restrict__ bias2, const float* __restrict__ bias3,
             void* __restrict__ Cout2, void* __restrict__ Cout3,
             long sA, long sB, long sC, float* __restrict__ aux)
{
  __shared__ char smem[2][16384];
  // --- bijective XCD-chunk swizzle (nwg % 8 == 0 for every launch here) ---
  const int gx = gridDim.x, gy = gridDim.y;
  const int nwg = gx * gy * gridDim.z;
  const int qq = nwg >> 3;
  int hw = blockIdx.x + gx * (blockIdx.y + gy * blockIdx.z);
  int lg = (hw & 7) * qq + (hw >> 3);
  const int bx = lg % gx; lg /= gx;
  const int by = lg % gy;
  const int bz = lg / gy;

  const int t  = threadIdx.x;
  const int m0 = by * 128;
  const int n0 = bx * 128;
  A += (size_t)bz * sA + (size_t)m0 * lda;
  B += (size_t)bz * sB + (size_t)n0 * ldb;

  const int lane = t & 63;
  const int wv = t >> 6;
  const int wr = wv >> 1, wc = wv & 1;

  f32x4 acc[4][4];
  #pragma unroll
  for (int i = 0; i < 4; ++i)
    #pragma unroll
    for (int j = 0; j < 4; ++j) acc[i][j] = (f32x4)0.0f;

  auto STAGE = [&](int buf, int kt) {
    const bf16* a = A + kt * 32;
    const bf16* b = B + kt * 32;
    #pragma unroll
    for (int i = 0; i < 2; ++i) {
      const int chunk = i * 256 + t;
      const int row = chunk >> 2, gp = chunk & 3;
      const int gg = gp ^ ((row >> 1) & 3);
      __builtin_amdgcn_global_load_lds(
          (const __attribute__((address_space(1))) unsigned int*)(a + (size_t)row * lda + gg * 8),
          (__attribute__((address_space(3))) unsigned int*)(&smem[buf][chunk * 16]),
          16, 0, 0);
    }
    #pragma unroll
    for (int i = 0; i < 2; ++i) {
      const int chunk = i * 256 + t;
      const int row = chunk >> 2, gp = chunk & 3;
      const int gg = gp ^ ((row >> 1) & 3);
      __builtin_amdgcn_global_load_lds(
          (const __attribute__((address_space(1))) unsigned int*)(b + (size_t)row * ldb + gg * 8),
          (__attribute__((address_space(3))) unsigned int*)(&smem[buf][8192 + chunk * 16]),
          16, 0, 0);
    }
  };

  const int nk = K >> 5;
  STAGE(0, 0);
  int cur = 0;
  const int r16 = lane & 15;
  const int gxo = ((lane >> 4) ^ ((r16 >> 1) & 3)) * 16;
  const int arow = wr * 64 + r16;
  const int brow = wc * 64 + r16;

  for (int kt = 0; kt < nk; ++kt) {
    __syncthreads();
    if (kt + 1 < nk) STAGE(cur ^ 1, kt + 1);
    bf16x8 af[4], bg[4];
    #pragma unroll
    for (int i = 0; i < 4; ++i)
      af[i] = *reinterpret_cast<const bf16x8*>(&smem[cur][(arow + i * 16) * 64 + gxo]);
    #pragma unroll
    for (int j = 0; j < 4; ++j)
      bg[j] = *reinterpret_cast<const bf16x8*>(&smem[cur][8192 + (brow + j * 16) * 64 + gxo]);
    #pragma unroll
    for (int i = 0; i < 4; ++i)
      #pragma unroll
      for (int j = 0; j < 4; ++j)
        acc[i][j] = __builtin_amdgcn_mfma_f32_16x16x32_bf16(af[i], bg[j], acc[i][j], 0, 0, 0);
    cur ^= 1;
  }

  // Epilogue. C/D map: col = lane&15, row = (lane>>4)*4 + reg.
  const int mq = (lane >> 4) * 4;
  const int nc = lane & 15;
  #pragma unroll
  for (int i = 0; i < 4; ++i) {
    float rs[4] = {0.0f, 0.0f, 0.0f, 0.0f};   // EPI 6 row partials
    #pragma unroll
    for (int j = 0; j < 4; ++j) {
      const int mm = m0 + wr * 64 + i * 16 + mq;
      const int nn = n0 + wc * 64 + j * 16 + nc;
      const f32x4 v = acc[i][j];
      if (EPI == 0) {
        const float bi = bias[nn];
        bf16* o = (bf16*)Cout;
        #pragma unroll
        for (int q = 0; q < 4; ++q)
          o[(size_t)(mm + q) * ldc + nn] = __float2bfloat16(v[q] + bi);
      } else if (EPI == 4) {
        const float bi = bias[nn];
        const int b = mm >> 12, ms = mm & (NSP - 1);
        const size_t off = ((size_t)b * C_DIM + nn) * NSP + ms;
        float* o = (float*)Cout + off;
        const float* r = resid + off;
        #pragma unroll
        for (int q = 0; q < 4; ++q) o[q] = v[q] + bi + r[q];
      } else if (EPI == 5) {
        const int sec = nn >> 9;
        const int nl  = nn & 511;
        if (sec == 0) {
          const float bi = bias[nl];
          bf16* o = (bf16*)Cout;
          #pragma unroll
          for (int q = 0; q < 4; ++q)
            o[(size_t)(mm + q) * 512 + nl] = __float2bfloat16((v[q] + bi) * scale);
        } else if (sec == 1) {
          const float bi = bias2[nl];
          bf16* o = (bf16*)Cout2;
          #pragma unroll
          for (int q = 0; q < 4; ++q)
            o[(size_t)(mm + q) * 512 + nl] = __float2bfloat16(v[q] + bi);
        } else {
          const float bi = bias3[nl];
          const int b = mm >> 12, ms = mm & (NSP - 1);
          bf16* o = (bf16*)Cout3 + ((size_t)b * C_DIM + nl) * NSP + ms;
          #pragma unroll
          for (int q = 0; q < 4; ++q) o[q] = __float2bfloat16(v[q] + bi);
        }
      } else if (EPI == 6) {
        // P = exp(S) (no max subtraction: |S| < ~1 by construction), + row partials
        bf16* o = (bf16*)Cout + (size_t)bz * sC;
        #pragma unroll
        for (int q = 0; q < 4; ++q) {
          const float e = __expf(v[q]);
          o[(size_t)(mm + q) * ldc + nn] = __float2bfloat16(e);
          rs[q] += e;
        }
      } else {  // EPI == 7: z with 1/l row scale
        bf16* o = (bf16*)Cout;
        #pragma unroll
        for (int q = 0; q < 4; ++q) {
          const float li = aux[(size_t)bz * NSP + mm + q];
          o[((size_t)bz * NSP + mm + q) * 512 + nn] = __float2bfloat16(v[q] * li);
        }
      }
    }
    if (EPI == 6) {
      // butterfly over the 16 col-lanes (masks 1,2,4,8 stay within 16-lane group)
      #pragma unroll
      for (int msk = 1; msk < 16; msk <<= 1)
        #pragma unroll
        for (int q = 0; q < 4; ++q) rs[q] += __shfl_xor(rs[q], msk);
      if (r16 == 0) {
        const int mm = m0 + wr * 64 + i * 16 + mq;
        #pragma unroll
        for (int q = 0; q < 4; ++q)
          aux[((size_t)bz * NSP + mm + q) * 64 + bx * 2 + wc] = rs[q];
      }
    }
  }
}

extern "C" void kernel_launch(void* const* d_in, const int* in_sizes, int n_in,
                              void* d_out, int out_size, void* d_ws, size_t ws_size,
                              hipStream_t stream)
{
  const float* x     = (const float*)d_in[0];
  const float* w_th  = (const float*)d_in[1];
  const float* b_th  = (const float*)d_in[2];
  const float* w_ph  = (const float*)d_in[3];
  const float* b_ph  = (const float*)d_in[4];
  const float* w_g   = (const float*)d_in[5];
  const float* b_g   = (const float*)d_in[6];
  const float* w_out = (const float*)d_in[7];
  const float* b_out = (const float*)d_in[8];

  const size_t NC = (size_t)16384 * C_DIM;
  char* p = (char*)d_ws;
  auto take = [&](size_t bytes) {
    char* r = p; p += (bytes + 255) & ~(size_t)255; return r;
  };
  bf16* XT   = (bf16*)take(NC * 2);
  bf16* YT   = (bf16*)take(NC * 2);
  bf16* THT  = (bf16*)take(NC * 2);   // pre-scaled theta
  bf16* PHT  = (bf16*)take(NC * 2);
  bf16* G2   = (bf16*)take(NC * 2);   // (B,C,N)
  bf16* ZT   = (bf16*)take(NC * 2);
  bf16* WCAT = (bf16*)take((size_t)1536 * 512 * 2);  // [th|ph|g]
  bf16* WG   = (bf16*)take((size_t)512 * 512 * 2);
  bf16* WOUT = (bf16*)take((size_t)512 * 512 * 2);
  float* Lp  = (float*)take((size_t)4 * NSP * 64 * 4);  // 4 MB row partials
  float* Li  = (float*)take((size_t)4 * NSP * 4);       // 64 KB 1/l
  const size_t used = (size_t)(p - (char*)d_ws);
  const size_t S1 = (size_t)NSP * NSP * 2;              // one batch of P, bf16
  const bool big = ws_size >= used + 4 * S1 + 1024;
  bf16* S = (bf16*)take(big ? 4 * S1 : S1);

  const dim3 blk(256);
  const float scale = 0.044194173824159216f;  // 512^-0.5
  const long sact = (long)NSP * C_DIM;
  const long sS   = (long)NSP * NSP;

  cvt_bf16<<<dim3(256), blk, 0, stream>>>(w_th,  WCAT);
  cvt_bf16<<<dim3(256), blk, 0, stream>>>(w_ph,  WCAT + (size_t)512 * 512);
  cvt_bf16<<<dim3(256), blk, 0, stream>>>(w_g,   WCAT + (size_t)1024 * 512);
  cvt_bf16<<<dim3(256), blk, 0, stream>>>(w_g,   WG);
  cvt_bf16<<<dim3(256), blk, 0, stream>>>(w_out, WOUT);

  transpose_x<<<dim3(NSP / 32, C_DIM / 32, 4), blk, 0, stream>>>(x, XT);

  // Y = g-conv(x)
  gemm_nt<0><<<dim3(4, 128), blk, 0, stream>>>(XT, WG, b_g, nullptr, YT,
      512, 512, 512, 512, 1.0f, nullptr, nullptr, nullptr, nullptr, 0, 0, 0, nullptr);
  // fused theta(scaled)/phi/g from Y
  gemm_nt<5><<<dim3(12, 128), blk, 0, stream>>>(YT, WCAT, b_th, nullptr, THT,
      512, 512, 512, 512, scale, b_ph, b_g, PHT, G2, 0, 0, 0, nullptr);

  if (big) {
    // P = exp(theta^T phi) with row partials
    gemm_nt<6><<<dim3(32, 32, 4), blk, 0, stream>>>(THT, PHT, nullptr, nullptr, S,
        512, 512, 512, NSP, 1.0f, nullptr, nullptr, nullptr, nullptr, sact, sact, sS, Lp);
    lreduce<<<dim3(64), blk, 0, stream>>>(Lp, Li);
    // Z[n_row, c] = (sum_m P[n,m] G2[c,m]) / l[n]
    gemm_nt<7><<<dim3(4, 32, 4), blk, 0, stream>>>(S, G2, nullptr, nullptr, ZT,
        4096, 4096, 4096, 512, 1.0f, nullptr, nullptr, nullptr, nullptr, sS, sact, 0, Li);
  } else {
    for (int b = 0; b < 4; ++b) {
      gemm_nt<6><<<dim3(32, 32, 1), blk, 0, stream>>>(THT + sact * b, PHT + sact * b,
          nullptr, nullptr, S, 512, 512, 512, NSP, 1.0f, nullptr, nullptr, nullptr, nullptr,
          0, 0, 0, Lp + (size_t)b * NSP * 64);
      lreduce<<<dim3(16), blk, 0, stream>>>(Lp + (size_t)b * NSP * 64, Li + (size_t)b * NSP);
      gemm_nt<7><<<dim3(4, 32, 1), blk, 0, stream>>>(S, G2 + sact * b, nullptr, nullptr,
          (bf16*)ZT + sact * b, 4096, 4096, 4096, 512, 1.0f, nullptr, nullptr, nullptr, nullptr,
          0, 0, 0, Li + (size_t)b * NSP);
    }
  }

  // out = x + out-conv(z)
  gemm_nt<4><<<dim3(4, 128), blk, 0, stream>>>(ZT, WOUT, b_out, x, d_out,
      512, 512, 512, 512, 1.0f, nullptr, nullptr, nullptr, nullptr, 0, 0, 0, nullptr);
}

// Round 5
// 277.652 us; speedup vs baseline: 1.8143x; 1.2487x over previous
//
#include <hip/hip_runtime.h>
#include <hip/hip_bf16.h>

typedef __hip_bfloat16 bf16;
typedef __attribute__((ext_vector_type(8))) short          bf16x8;
typedef __attribute__((ext_vector_type(4))) float          f32x4;
typedef __attribute__((ext_vector_type(4))) int            i32x4;
typedef __attribute__((ext_vector_type(8))) int            i32x8;

#define C_DIM 512
#define NSP   4096

__device__ __forceinline__ unsigned char f2fp8(float x) {
  return (unsigned char)(__builtin_amdgcn_cvt_pk_fp8_f32(x, x, 0, false) & 0xFF);
}

// ---------------- f32 -> bf16 convert (512x512 weight) ----------------
__global__ __launch_bounds__(256) void cvt_bf16(const float* __restrict__ s,
                                                bf16* __restrict__ d) {
  const int i = (blockIdx.x * 256 + threadIdx.x) * 4;
  const float4 v = *reinterpret_cast<const float4*>(s + i);
  d[i + 0] = __float2bfloat16(v.x);
  d[i + 1] = __float2bfloat16(v.y);
  d[i + 2] = __float2bfloat16(v.z);
  d[i + 3] = __float2bfloat16(v.w);
}

// ---------------- x (B,C,N) f32 -> XT (B*N, C) bf16 ----------------
__global__ __launch_bounds__(256) void transpose_x(const float* __restrict__ x,
                                                   bf16* __restrict__ xt) {
  __shared__ float tile[32][33];
  const int n0 = blockIdx.x * 32, c0 = blockIdx.y * 32, b = blockIdx.z;
  const int tx = threadIdx.x & 31, ty = threadIdx.x >> 5;
  const float* src = x + ((size_t)b * C_DIM + c0) * NSP + n0;
  #pragma unroll
  for (int i = 0; i < 32; i += 8)
    tile[ty + i][tx] = src[(size_t)(ty + i) * NSP + tx];
  __syncthreads();
  bf16* dst = xt + ((size_t)b * NSP + n0) * C_DIM + c0;
  #pragma unroll
  for (int i = 0; i < 32; i += 8)
    dst[(size_t)(ty + i) * C_DIM + tx] = __float2bfloat16(tile[tx][ty + i]);
}

// ---------------- Linv: Lp[16384][64] partial sums -> 1/rowsum ----------------
__global__ __launch_bounds__(256) void lreduce(const float* __restrict__ Lp,
                                               float* __restrict__ Linv) {
  const int r = blockIdx.x * 256 + threadIdx.x;
  const float4* p = reinterpret_cast<const float4*>(Lp + (size_t)r * 64);
  float s = 0.0f;
  #pragma unroll
  for (int i = 0; i < 16; ++i) { const float4 v = p[i]; s += (v.x + v.y) + (v.z + v.w); }
  Linv[r] = 1.0f / s;
}

// ======================= bf16 NT GEMM (convs) =======================
// 128x128 tile, BK=32, 256 thr, 16x16x32 bf16 MFMA, 2-phase dbuf, XCD swizzle.
// EPI: 0 bf16 +bias (row-major ldc)
//      4 f32  +bias+resid, transposed store (out[(b*C+n)*NSP + m], b=m>>12)
//      5 fused: n<512 -> TH8 fp8 (v+bias)*sqscale; <1024 -> PH8 fp8 (v+bias2)*sqscale
//               else  -> G8 fp8 (v+bias3), transposed (B,C,N) packed u32 stores
template<int EPI>
__global__ __launch_bounds__(256)
void gemm_nt(const bf16* __restrict__ A, const bf16* __restrict__ B,
             const float* __restrict__ bias, const float* __restrict__ resid,
             void* __restrict__ Cout,
             int K, int lda, int ldb, int ldc, float sqscale,
             const float* __restrict__ bias2, const float* __restrict__ bias3,
             void* __restrict__ Cout2, void* __restrict__ Cout3)
{
  __shared__ char smem[2][16384];
  const int gx = gridDim.x, gy = gridDim.y;
  const int nwg = gx * gy * gridDim.z;
  const int qq = nwg >> 3;
  int hw = blockIdx.x + gx * (blockIdx.y + gy * blockIdx.z);
  int lg = (hw & 7) * qq + (hw >> 3);
  const int bx = lg % gx; lg /= gx;
  const int by = lg % gy;

  const int t  = threadIdx.x;
  const int m0 = by * 128;
  const int n0 = bx * 128;
  A += (size_t)m0 * lda;
  B += (size_t)n0 * ldb;

  const int lane = t & 63;
  const int wv = t >> 6;
  const int wr = wv >> 1, wc = wv & 1;

  f32x4 acc[4][4];
  #pragma unroll
  for (int i = 0; i < 4; ++i)
    #pragma unroll
    for (int j = 0; j < 4; ++j) acc[i][j] = (f32x4)0.0f;

  auto STAGE = [&](int buf, int kt) {
    const bf16* a = A + kt * 32;
    const bf16* b = B + kt * 32;
    #pragma unroll
    for (int i = 0; i < 2; ++i) {
      const int chunk = i * 256 + t;
      const int row = chunk >> 2, gp = chunk & 3;
      const int gg = gp ^ ((row >> 1) & 3);
      __builtin_amdgcn_global_load_lds(
          (const __attribute__((address_space(1))) unsigned int*)(a + (size_t)row * lda + gg * 8),
          (__attribute__((address_space(3))) unsigned int*)(&smem[buf][chunk * 16]),
          16, 0, 0);
    }
    #pragma unroll
    for (int i = 0; i < 2; ++i) {
      const int chunk = i * 256 + t;
      const int row = chunk >> 2, gp = chunk & 3;
      const int gg = gp ^ ((row >> 1) & 3);
      __builtin_amdgcn_global_load_lds(
          (const __attribute__((address_space(1))) unsigned int*)(b + (size_t)row * ldb + gg * 8),
          (__attribute__((address_space(3))) unsigned int*)(&smem[buf][8192 + chunk * 16]),
          16, 0, 0);
    }
  };

  const int nk = K >> 5;
  STAGE(0, 0);
  int cur = 0;
  const int r16 = lane & 15;
  const int gxo = ((lane >> 4) ^ ((r16 >> 1) & 3)) * 16;
  const int arow = wr * 64 + r16;
  const int brow = wc * 64 + r16;

  for (int kt = 0; kt < nk; ++kt) {
    __syncthreads();
    if (kt + 1 < nk) STAGE(cur ^ 1, kt + 1);
    bf16x8 af[4], bg[4];
    #pragma unroll
    for (int i = 0; i < 4; ++i)
      af[i] = *reinterpret_cast<const bf16x8*>(&smem[cur][(arow + i * 16) * 64 + gxo]);
    #pragma unroll
    for (int j = 0; j < 4; ++j)
      bg[j] = *reinterpret_cast<const bf16x8*>(&smem[cur][8192 + (brow + j * 16) * 64 + gxo]);
    #pragma unroll
    for (int i = 0; i < 4; ++i)
      #pragma unroll
      for (int j = 0; j < 4; ++j)
        acc[i][j] = __builtin_amdgcn_mfma_f32_16x16x32_bf16(af[i], bg[j], acc[i][j], 0, 0, 0);
    cur ^= 1;
  }

  const int mq = (lane >> 4) * 4;
  const int nc = lane & 15;
  #pragma unroll
  for (int i = 0; i < 4; ++i) {
    #pragma unroll
    for (int j = 0; j < 4; ++j) {
      const int mm = m0 + wr * 64 + i * 16 + mq;
      const int nn = n0 + wc * 64 + j * 16 + nc;
      const f32x4 v = acc[i][j];
      if (EPI == 0) {
        const float bi = bias[nn];
        bf16* o = (bf16*)Cout;
        #pragma unroll
        for (int q = 0; q < 4; ++q)
          o[(size_t)(mm + q) * ldc + nn] = __float2bfloat16(v[q] + bi);
      } else if (EPI == 4) {
        const float bi = bias[nn];
        const int b = mm >> 12, ms = mm & (NSP - 1);
        const size_t off = ((size_t)b * C_DIM + nn) * NSP + ms;
        float* o = (float*)Cout + off;
        const float* r = resid + off;
        #pragma unroll
        for (int q = 0; q < 4; ++q) o[q] = v[q] + bi + r[q];
      } else {  // EPI == 5
        const int sec = nn >> 9;
        const int nl  = nn & 511;
        if (sec == 0) {
          const float bi = bias[nl];
          unsigned char* o = (unsigned char*)Cout;
          #pragma unroll
          for (int q = 0; q < 4; ++q)
            o[(size_t)(mm + q) * 512 + nl] = f2fp8((v[q] + bi) * sqscale);
        } else if (sec == 1) {
          const float bi = bias2[nl];
          unsigned char* o = (unsigned char*)Cout2;
          #pragma unroll
          for (int q = 0; q < 4; ++q)
            o[(size_t)(mm + q) * 512 + nl] = f2fp8((v[q] + bi) * sqscale);
        } else {
          const float bi = bias3[nl];
          const int b = mm >> 12, ms = mm & (NSP - 1);
          unsigned int pk = __builtin_amdgcn_cvt_pk_fp8_f32(v[0] + bi, v[1] + bi, 0, false);
          pk = __builtin_amdgcn_cvt_pk_fp8_f32(v[2] + bi, v[3] + bi, pk, true);
          *(unsigned int*)((unsigned char*)Cout3 + ((size_t)b * C_DIM + nl) * NSP + ms) = pk;
        }
      }
    }
  }
}

// ======================= fp8 MX NT GEMM (scores / z) =======================
// C[m,n] = sum_k A[m,k]*B[n,k], A/B fp8 e4m3, 128x128 tile, BK=128,
// mfma_scale_f32_16x16x128_f8f6f4 with unit scales (0x7F in every byte).
// EPI 0: P = exp(v) fp8 -> Cout(+bz*sC), row partials -> aux[(bz*4096+row)*64+bx*2+wc]
// EPI 1: bf16 v * aux[bz*4096+row] -> ((bz*4096+row)*512 + nn)
template<int EPI>
__global__ __launch_bounds__(256)
void gemm_f8(const unsigned char* __restrict__ A, const unsigned char* __restrict__ B,
             void* __restrict__ Cout, int K, int lda, int ldb, int ldc,
             long sA, long sB, long sC, float* __restrict__ aux)
{
  __shared__ char smem[2][32768];   // A 16K | B 16K per buf
  const int gx = gridDim.x, gy = gridDim.y;
  const int nwg = gx * gy * gridDim.z;
  const int qq = nwg >> 3;
  int hw = blockIdx.x + gx * (blockIdx.y + gy * blockIdx.z);
  int lg = (hw & 7) * qq + (hw >> 3);
  const int bx = lg % gx; lg /= gx;
  const int by = lg % gy;
  const int bz = lg / gy;

  const int t  = threadIdx.x;
  const int m0 = by * 128;
  const int n0 = bx * 128;
  A += (size_t)bz * sA + (size_t)m0 * lda;
  B += (size_t)bz * sB + (size_t)n0 * ldb;

  const int lane = t & 63;
  const int wv = t >> 6;
  const int wr = wv >> 1, wc = wv & 1;
  const int r16 = lane & 15, g4 = lane >> 4;

  f32x4 acc[4][4];
  #pragma unroll
  for (int i = 0; i < 4; ++i)
    #pragma unroll
    for (int j = 0; j < 4; ++j) acc[i][j] = (f32x4)0.0f;

  // stage 128 rows x 128 B; granule XOR-swizzle g^(row&7), source pre-swizzled
  auto STAGE = [&](int buf, int kt) {
    const unsigned char* a = A + kt * 128;
    const unsigned char* b = B + kt * 128;
    #pragma unroll
    for (int i = 0; i < 4; ++i) {
      const int chunk = i * 256 + t;            // 0..1023
      const int row = chunk >> 3, gp = chunk & 7;
      const int gg = gp ^ (row & 7);
      __builtin_amdgcn_global_load_lds(
          (const __attribute__((address_space(1))) unsigned int*)(a + (size_t)row * lda + gg * 16),
          (__attribute__((address_space(3))) unsigned int*)(&smem[buf][chunk * 16]),
          16, 0, 0);
    }
    #pragma unroll
    for (int i = 0; i < 4; ++i) {
      const int chunk = i * 256 + t;
      const int row = chunk >> 3, gp = chunk & 7;
      const int gg = gp ^ (row & 7);
      __builtin_amdgcn_global_load_lds(
          (const __attribute__((address_space(1))) unsigned int*)(b + (size_t)row * ldb + gg * 16),
          (__attribute__((address_space(3))) unsigned int*)(&smem[buf][16384 + chunk * 16]),
          16, 0, 0);
    }
  };

  const int nk = K >> 7;
  STAGE(0, 0);
  int cur = 0;
  const int p0 = g4 * 2;                        // lane's first 16B granule (k block)

  for (int kt = 0; kt < nk; ++kt) {
    __syncthreads();
    if (kt + 1 < nk) STAGE(cur ^ 1, kt + 1);
    i32x8 af[4], bg[4];
    #pragma unroll
    for (int i = 0; i < 4; ++i) {
      const int row = wr * 64 + i * 16 + r16;
      const i32x4 lo = *(const i32x4*)(&smem[cur][row * 128 + ((p0    ) ^ (row & 7)) * 16]);
      const i32x4 hi = *(const i32x4*)(&smem[cur][row * 128 + ((p0 + 1) ^ (row & 7)) * 16]);
      #pragma unroll
      for (int q = 0; q < 4; ++q) { af[i][q] = lo[q]; af[i][4 + q] = hi[q]; }
    }
    #pragma unroll
    for (int j = 0; j < 4; ++j) {
      const int row = wc * 64 + j * 16 + r16;
      const i32x4 lo = *(const i32x4*)(&smem[cur][16384 + row * 128 + ((p0    ) ^ (row & 7)) * 16]);
      const i32x4 hi = *(const i32x4*)(&smem[cur][16384 + row * 128 + ((p0 + 1) ^ (row & 7)) * 16]);
      #pragma unroll
      for (int q = 0; q < 4; ++q) { bg[j][q] = lo[q]; bg[j][4 + q] = hi[q]; }
    }
    #pragma unroll
    for (int i = 0; i < 4; ++i)
      #pragma unroll
      for (int j = 0; j < 4; ++j)
        acc[i][j] = __builtin_amdgcn_mfma_scale_f32_16x16x128_f8f6f4(
            af[i], bg[j], acc[i][j], 0, 0, 0, 0x7F7F7F7Fu, 0, 0x7F7F7F7Fu);
    cur ^= 1;
  }

  // C/D map: col = lane&15, row = (lane>>4)*4 + reg.
  const int mq = g4 * 4;
  #pragma unroll
  for (int i = 0; i < 4; ++i) {
    float rs[4] = {0.0f, 0.0f, 0.0f, 0.0f};
    #pragma unroll
    for (int j = 0; j < 4; ++j) {
      const int mm = m0 + wr * 64 + i * 16 + mq;
      const int nn = n0 + wc * 64 + j * 16 + r16;
      const f32x4 v = acc[i][j];
      if (EPI == 0) {
        unsigned char* o = (unsigned char*)Cout + (size_t)bz * sC;
        #pragma unroll
        for (int q = 0; q < 4; ++q) {
          const float e = __expf(v[q]);
          o[(size_t)(mm + q) * ldc + nn] = f2fp8(e);
          rs[q] += e;
        }
      } else {
        bf16* o = (bf16*)Cout;
        #pragma unroll
        for (int q = 0; q < 4; ++q) {
          const float li = aux[(size_t)bz * NSP + mm + q];
          o[((size_t)bz * NSP + mm + q) * 512 + nn] = __float2bfloat16(v[q] * li);
        }
      }
    }
    if (EPI == 0) {
      #pragma unroll
      for (int msk = 1; msk < 16; msk <<= 1)
        #pragma unroll
        for (int q = 0; q < 4; ++q) rs[q] += __shfl_xor(rs[q], msk);
      if (r16 == 0) {
        const int mm = m0 + wr * 64 + i * 16 + mq;
        #pragma unroll
        for (int q = 0; q < 4; ++q)
          aux[((size_t)bz * NSP + mm + q) * 64 + bx * 2 + wc] = rs[q];
      }
    }
  }
}

extern "C" void kernel_launch(void* const* d_in, const int* in_sizes, int n_in,
                              void* d_out, int out_size, void* d_ws, size_t ws_size,
                              hipStream_t stream)
{
  const float* x     = (const float*)d_in[0];
  const float* w_th  = (const float*)d_in[1];
  const float* b_th  = (const float*)d_in[2];
  const float* w_ph  = (const float*)d_in[3];
  const float* b_ph  = (const float*)d_in[4];
  const float* w_g   = (const float*)d_in[5];
  const float* b_g   = (const float*)d_in[6];
  const float* w_out = (const float*)d_in[7];
  const float* b_out = (const float*)d_in[8];

  const size_t NC = (size_t)16384 * C_DIM;
  char* p = (char*)d_ws;
  auto take = [&](size_t bytes) {
    char* r = p; p += (bytes + 255) & ~(size_t)255; return r;
  };
  bf16* XT  = (bf16*)take(NC * 2);
  bf16* YT  = (bf16*)take(NC * 2);
  bf16* ZT  = (bf16*)take(NC * 2);
  unsigned char* TH8 = (unsigned char*)take(NC);        // (B*N, C) fp8, pre-scaled
  unsigned char* PH8 = (unsigned char*)take(NC);        // (B*N, C) fp8, pre-scaled
  unsigned char* G8  = (unsigned char*)take(NC);        // (B, C, N) fp8
  unsigned char* P8  = (unsigned char*)take((size_t)4 * NSP * NSP);  // 64 MB
  bf16* WCAT = (bf16*)take((size_t)1536 * 512 * 2);
  bf16* WG   = (bf16*)take((size_t)512 * 512 * 2);
  bf16* WOUT = (bf16*)take((size_t)512 * 512 * 2);
  float* Lp  = (float*)take((size_t)4 * NSP * 64 * 4);
  float* Li  = (float*)take((size_t)4 * NSP * 4);

  const dim3 blk(256);
  const float sqscale = 0.21022410381342864f;  // 512^-0.25
  const long sact = (long)NSP * C_DIM;
  const long sS   = (long)NSP * NSP;

  cvt_bf16<<<dim3(256), blk, 0, stream>>>(w_th,  WCAT);
  cvt_bf16<<<dim3(256), blk, 0, stream>>>(w_ph,  WCAT + (size_t)512 * 512);
  cvt_bf16<<<dim3(256), blk, 0, stream>>>(w_g,   WCAT + (size_t)1024 * 512);
  cvt_bf16<<<dim3(256), blk, 0, stream>>>(w_g,   WG);
  cvt_bf16<<<dim3(256), blk, 0, stream>>>(w_out, WOUT);

  transpose_x<<<dim3(NSP / 32, C_DIM / 32, 4), blk, 0, stream>>>(x, XT);

  // Y = g-conv(x), bf16
  gemm_nt<0><<<dim3(4, 128), blk, 0, stream>>>(XT, WG, b_g, nullptr, YT,
      512, 512, 512, 512, 1.0f, nullptr, nullptr, nullptr, nullptr);
  // fused theta/phi (fp8, *512^-1/4) and g (fp8, (B,C,N)) from Y
  gemm_nt<5><<<dim3(12, 128), blk, 0, stream>>>(YT, WCAT, b_th, nullptr, TH8,
      512, 512, 512, 512, sqscale, b_ph, b_g, PH8, G8);

  // P = exp(theta^T phi) fp8 + row partials
  gemm_f8<0><<<dim3(32, 32, 4), blk, 0, stream>>>(TH8, PH8, P8,
      512, 512, 512, NSP, sact, sact, sS, Lp);
  lreduce<<<dim3(64), blk, 0, stream>>>(Lp, Li);
  // Z[n, c] = (sum_m P[n,m] G8[c,m]) / l[n]  -> ZT bf16 (B*N, C)
  gemm_f8<1><<<dim3(4, 32, 4), blk, 0, stream>>>(P8, G8, ZT,
      4096, 4096, 4096, 512, sS, sact, 0, Li);

  // out = x + out-conv(z)
  gemm_nt<4><<<dim3(4, 128), blk, 0, stream>>>(ZT, WOUT, b_out, x, d_out,
      512, 512, 512, 512, 1.0f, nullptr, nullptr, nullptr, nullptr);
}